// Round 7
// baseline (1797.614 us; speedup 1.0000x reference)
//
#include <hip/hip_runtime.h>

#define N_NODES 50000
#define N_GENES 256
#define N_EDGES 800000
#define NUM_ITERS 10
#define SCAN_BLK 1024
#define N_SCAN_BLKS ((N_NODES + SCAN_BLK - 1) / SCAN_BLK)   // 49

#define SLICE_G 32                    // genes per slice (bf16 slice = 3.2 MB < 4 MB L2)
#define N_SLICES 8                    // one slice per XCD
#define NODES_PER_WAVE 8
#define NODES_PER_BLOCK 32            // 4 waves x 8 nodes
#define BLKS_PER_SLICE ((N_NODES + NODES_PER_BLOCK - 1) / NODES_PER_BLOCK)  // 1563
#define PROP_GRID (BLKS_PER_SLICE * N_SLICES)                               // 12504

typedef unsigned short u16;
struct u16x4 { u16 x, y, z, w; };

static __device__ __forceinline__ float bf2f(u16 b) {
    return __uint_as_float(((unsigned)b) << 16);
}
static __device__ __forceinline__ u16 f2bf(float f) {
    unsigned u = __float_as_uint(f);
    return (u16)((u + 0x7fffu + ((u >> 16) & 1u)) >> 16);   // RNE
}

// ---------------- CSR build (once per launch) -----------------------------

__global__ void hist_kernel(const int* __restrict__ dst, int* __restrict__ counts) {
    int e = blockIdx.x * blockDim.x + threadIdx.x;
    if (e < N_EDGES) atomicAdd(&counts[dst[e]], 1);
}

__global__ __launch_bounds__(SCAN_BLK) void scan1_kernel(
        const int* __restrict__ counts, int* __restrict__ offs,
        int* __restrict__ bsums) {
    int i = blockIdx.x * SCAN_BLK + threadIdx.x;
    int lane = threadIdx.x & 63, wid = threadIdx.x >> 6;
    int v = (i < N_NODES) ? counts[i] : 0;
    int x = v;
    #pragma unroll
    for (int o = 1; o < 64; o <<= 1) {
        int t = __shfl_up(x, o, 64);
        if (lane >= o) x += t;
    }
    __shared__ int wsum[16];
    if (lane == 63) wsum[wid] = x;
    __syncthreads();
    if (wid == 0 && lane < 16) {
        int y = wsum[lane];
        #pragma unroll
        for (int o = 1; o < 16; o <<= 1) {
            int t = __shfl_up(y, o, 64);
            if (lane >= o) y += t;
        }
        wsum[lane] = y;
    }
    __syncthreads();
    int pref = (wid > 0) ? wsum[wid - 1] : 0;
    int incl = x + pref;
    if (i < N_NODES) offs[i] = incl - v;
    if (threadIdx.x == SCAN_BLK - 1) bsums[blockIdx.x] = incl;
}

__global__ void scan2_kernel(const int* __restrict__ bsums,
                             int* __restrict__ bpref,
                             int* __restrict__ offs_total) {
    int lane = threadIdx.x;  // 64 threads
    int v = (lane < N_SCAN_BLKS) ? bsums[lane] : 0;
    int x = v;
    #pragma unroll
    for (int o = 1; o < 64; o <<= 1) {
        int t = __shfl_up(x, o, 64);
        if (lane >= o) x += t;
    }
    if (lane < N_SCAN_BLKS) bpref[lane] = x - v;
    if (lane == 63) offs_total[0] = x;
}

__global__ __launch_bounds__(SCAN_BLK) void scan3_kernel(
        int* __restrict__ offs, const int* __restrict__ bpref,
        int* __restrict__ cursor) {
    int i = blockIdx.x * SCAN_BLK + threadIdx.x;
    if (i < N_NODES) {
        int o = offs[i] + bpref[blockIdx.x];
        offs[i] = o;
        cursor[i] = o;
    }
}

// CSR payload: u16 src + f32 weight (f32 weights keep per-edge numerics exact)
__global__ void scatter_kernel(const int* __restrict__ dst,
                               const int* __restrict__ src,
                               const float* __restrict__ w,
                               int* __restrict__ cursor,
                               u16* __restrict__ ssrc,
                               float* __restrict__ sw) {
    int e = blockIdx.x * blockDim.x + threadIdx.x;
    if (e < N_EDGES) {
        int d = dst[e];
        int p = atomicAdd(&cursor[d], 1);
        ssrc[p] = (u16)src[e];
        sw[p]   = w[e];
    }
}

// x (f32 node-major) -> xs (bf16 slice-major [8][N][32]); 8 genes per thread
__global__ __launch_bounds__(256) void cvt_slice_kernel(const float* __restrict__ x,
                                                        u16* __restrict__ xs) {
    int base = (blockIdx.x * blockDim.x + threadIdx.x) * 8;
    if (base >= N_NODES * N_GENES) return;
    int node = base >> 8;
    int gene = base & 255;
    int slice = gene >> 5;
    int g = gene & 31;             // 8-aligned within slice
    float4 a = *reinterpret_cast<const float4*>(&x[base]);
    float4 b = *reinterpret_cast<const float4*>(&x[base + 4]);
    u16x4 r0 = { f2bf(a.x), f2bf(a.y), f2bf(a.z), f2bf(a.w) };
    u16x4 r1 = { f2bf(b.x), f2bf(b.y), f2bf(b.z), f2bf(b.w) };
    size_t o = (size_t)slice * N_NODES * SLICE_G + (size_t)node * SLICE_G + g;
    *reinterpret_cast<u16x4*>(&xs[o])     = r0;
    *reinterpret_cast<u16x4*>(&xs[o + 4]) = r1;
}

// ---------------- Gene-sliced propagation ---------------------------------
// Slice s (32 genes bf16, 3.2 MB over all nodes) is touched only by blocks
// with blockIdx%8 == s -> pinned to one XCD's 4 MB L2. All streaming traffic
// (edge meta, clamp source, stores) is nontemporal so only the gathered
// slice allocates. Wave: 4 edge-slots x 16 lanes (u16x2 = 2 genes/lane).

__global__ __launch_bounds__(256) void prop_s_b(
        const u16* __restrict__ hin,   // [8][N][32]
        const u16* __restrict__ xs,    // [8][N][32]
        const int* __restrict__ offsets,
        const u16* __restrict__ ssrc,
        const float* __restrict__ sw,
        u16* __restrict__ out) {       // [8][N][32]
    int slice = blockIdx.x & 7;
    int blk   = blockIdx.x >> 3;
    int wid = threadIdx.x >> 6, lane = threadIdx.x & 63;
    int slot = lane >> 4;        // 0..3 edge slots
    int g2   = (lane & 15) << 1; // genes g2, g2+1
    const u16* hs = hin + (size_t)slice * N_NODES * SLICE_G;

    int node_base = blk * NODES_PER_BLOCK + wid * NODES_PER_WAVE;
    for (int n = 0; n < NODES_PER_WAVE; ++n) {
        int node = node_base + n;
        if (node >= N_NODES) break;
        int beg = offsets[node], end = offsets[node + 1];
        float ax = 0.f, ay = 0.f;

        for (int base = beg; base < end; base += 64) {
            int cnt = end - base;
            if (cnt > 64) cnt = 64;
            int sv = 0; float wv = 0.f;
            if (lane < cnt) {
                sv = __builtin_nontemporal_load(&ssrc[base + lane]);
                wv = __builtin_nontemporal_load(&sw[base + lane]);
            }
            int kmax = (cnt + 3) >> 2;   // 4 edges per k (one per slot)
            int k = 0;
            for (; k + 4 <= kmax; k += 4) {
                int e0 = (k + 0) * 4 + slot, e1 = (k + 1) * 4 + slot;
                int e2 = (k + 2) * 4 + slot, e3 = (k + 3) * 4 + slot;
                int   s0 = __shfl(sv, e0), s1 = __shfl(sv, e1);
                int   s2 = __shfl(sv, e2), s3 = __shfl(sv, e3);
                float w0 = __shfl(wv, e0), w1 = __shfl(wv, e1);
                float w2 = __shfl(wv, e2), w3 = __shfl(wv, e3);
                unsigned p0 = *reinterpret_cast<const unsigned*>(&hs[s0 * SLICE_G + g2]);
                unsigned p1 = *reinterpret_cast<const unsigned*>(&hs[s1 * SLICE_G + g2]);
                unsigned p2 = *reinterpret_cast<const unsigned*>(&hs[s2 * SLICE_G + g2]);
                unsigned p3 = *reinterpret_cast<const unsigned*>(&hs[s3 * SLICE_G + g2]);
                ax += w0 * bf2f((u16)p0) + w1 * bf2f((u16)p1)
                    + w2 * bf2f((u16)p2) + w3 * bf2f((u16)p3);
                ay += w0 * bf2f((u16)(p0 >> 16)) + w1 * bf2f((u16)(p1 >> 16))
                    + w2 * bf2f((u16)(p2 >> 16)) + w3 * bf2f((u16)(p3 >> 16));
            }
            for (; k < kmax; ++k) {
                int e = k * 4 + slot;
                int   s = __shfl(sv, e);
                float w = __shfl(wv, e);   // w==0 for padded lanes -> no-op
                unsigned p = *reinterpret_cast<const unsigned*>(&hs[s * SLICE_G + g2]);
                ax += w * bf2f((u16)p);
                ay += w * bf2f((u16)(p >> 16));
            }
        }

        ax += __shfl_xor(ax, 16); ax += __shfl_xor(ax, 32);
        ay += __shfl_xor(ay, 16); ay += __shfl_xor(ay, 32);

        if (slot == 0) {
            size_t o = (size_t)slice * N_NODES * SLICE_G + (size_t)node * SLICE_G + g2;
            unsigned ox = __builtin_nontemporal_load(reinterpret_cast<const unsigned*>(&xs[o]));
            u16 b0 = (u16)(ox & 0xFFFFu), b1 = (u16)(ox >> 16);
            u16 r0 = b0 ? b0 : f2bf(ax);   // x >= 0: bits==0 <=> value==0
            u16 r1 = b1 ? b1 : f2bf(ay);
            unsigned res = (unsigned)r0 | ((unsigned)r1 << 16);
            __builtin_nontemporal_store(res, reinterpret_cast<unsigned*>(&out[o]));
        }
    }
}

// Final iteration: same sliced gather, clamp with pristine f32 x, write f32
// node-major output.
__global__ __launch_bounds__(256) void prop_s_final(
        const u16* __restrict__ hin,
        const float* __restrict__ x,
        const int* __restrict__ offsets,
        const u16* __restrict__ ssrc,
        const float* __restrict__ sw,
        float* __restrict__ out) {
    int slice = blockIdx.x & 7;
    int blk   = blockIdx.x >> 3;
    int wid = threadIdx.x >> 6, lane = threadIdx.x & 63;
    int slot = lane >> 4;
    int g2   = (lane & 15) << 1;
    const u16* hs = hin + (size_t)slice * N_NODES * SLICE_G;

    int node_base = blk * NODES_PER_BLOCK + wid * NODES_PER_WAVE;
    for (int n = 0; n < NODES_PER_WAVE; ++n) {
        int node = node_base + n;
        if (node >= N_NODES) break;
        int beg = offsets[node], end = offsets[node + 1];
        float ax = 0.f, ay = 0.f;

        for (int base = beg; base < end; base += 64) {
            int cnt = end - base;
            if (cnt > 64) cnt = 64;
            int sv = 0; float wv = 0.f;
            if (lane < cnt) {
                sv = __builtin_nontemporal_load(&ssrc[base + lane]);
                wv = __builtin_nontemporal_load(&sw[base + lane]);
            }
            int kmax = (cnt + 3) >> 2;
            int k = 0;
            for (; k + 4 <= kmax; k += 4) {
                int e0 = (k + 0) * 4 + slot, e1 = (k + 1) * 4 + slot;
                int e2 = (k + 2) * 4 + slot, e3 = (k + 3) * 4 + slot;
                int   s0 = __shfl(sv, e0), s1 = __shfl(sv, e1);
                int   s2 = __shfl(sv, e2), s3 = __shfl(sv, e3);
                float w0 = __shfl(wv, e0), w1 = __shfl(wv, e1);
                float w2 = __shfl(wv, e2), w3 = __shfl(wv, e3);
                unsigned p0 = *reinterpret_cast<const unsigned*>(&hs[s0 * SLICE_G + g2]);
                unsigned p1 = *reinterpret_cast<const unsigned*>(&hs[s1 * SLICE_G + g2]);
                unsigned p2 = *reinterpret_cast<const unsigned*>(&hs[s2 * SLICE_G + g2]);
                unsigned p3 = *reinterpret_cast<const unsigned*>(&hs[s3 * SLICE_G + g2]);
                ax += w0 * bf2f((u16)p0) + w1 * bf2f((u16)p1)
                    + w2 * bf2f((u16)p2) + w3 * bf2f((u16)p3);
                ay += w0 * bf2f((u16)(p0 >> 16)) + w1 * bf2f((u16)(p1 >> 16))
                    + w2 * bf2f((u16)(p2 >> 16)) + w3 * bf2f((u16)(p3 >> 16));
            }
            for (; k < kmax; ++k) {
                int e = k * 4 + slot;
                int   s = __shfl(sv, e);
                float w = __shfl(wv, e);
                unsigned p = *reinterpret_cast<const unsigned*>(&hs[s * SLICE_G + g2]);
                ax += w * bf2f((u16)p);
                ay += w * bf2f((u16)(p >> 16));
            }
        }

        ax += __shfl_xor(ax, 16); ax += __shfl_xor(ax, 32);
        ay += __shfl_xor(ay, 16); ay += __shfl_xor(ay, 32);

        if (slot == 0) {
            size_t xo = (size_t)node * N_GENES + slice * SLICE_G + g2;
            float2 o = *reinterpret_cast<const float2*>(&x[xo]);
            float2 r;
            r.x = (o.x != 0.f) ? o.x : ax;
            r.y = (o.y != 0.f) ? o.y : ay;
            *reinterpret_cast<float2*>(&out[xo]) = r;
        }
    }
}

// --------------------------------------------------------------------------

static inline size_t align_up(size_t x, size_t a) { return (x + a - 1) & ~(a - 1); }

extern "C" void kernel_launch(void* const* d_in, const int* in_sizes, int n_in,
                              void* d_out, int out_size, void* d_ws, size_t ws_size,
                              hipStream_t stream) {
    const float* x    = (const float*)d_in[0];   // [N_NODES, N_GENES]
    const int*   eidx = (const int*)d_in[1];     // [2, N_EDGES]: row0 = dst, row1 = src
    const float* ew   = (const float*)d_in[2];   // [N_EDGES]
    float*       out  = (float*)d_out;

    const int* dst = eidx;
    const int* src = eidx + N_EDGES;

    // workspace layout (~57 MB)
    char* ws = (char*)d_ws;
    size_t off = 0;
    u16*   xs      = (u16*) (ws + off); off += align_up((size_t)N_NODES * N_GENES * 2, 256);
    u16*   hsA     = (u16*) (ws + off); off += align_up((size_t)N_NODES * N_GENES * 2, 256);
    u16*   ssrc    = (u16*) (ws + off); off += align_up((size_t)N_EDGES * 2, 256);
    float* swt     = (float*)(ws + off); off += align_up((size_t)N_EDGES * 4, 256);
    int*   counts  = (int*) (ws + off); off += align_up((size_t)N_NODES * 4, 256);
    int*   offsets = (int*) (ws + off); off += align_up((size_t)(N_NODES + 1) * 4, 256);
    int*   cursor  = (int*) (ws + off); off += align_up((size_t)N_NODES * 4, 256);
    int*   bsums   = (int*) (ws + off); off += align_up((size_t)N_SCAN_BLKS * 4, 256);
    int*   bpref   = (int*) (ws + off); off += align_up((size_t)N_SCAN_BLKS * 4, 256);
    (void)ws_size;

    u16* hsB = (u16*)d_out;   // d_out doubles as bf16 slice-major scratch

    // ---- build CSR by destination + slice-major bf16 copy of x ----
    hipMemsetAsync(counts, 0, (size_t)N_NODES * 4, stream);
    hist_kernel<<<(N_EDGES + 255) / 256, 256, 0, stream>>>(dst, counts);
    scan1_kernel<<<N_SCAN_BLKS, SCAN_BLK, 0, stream>>>(counts, offsets, bsums);
    scan2_kernel<<<1, 64, 0, stream>>>(bsums, bpref, &offsets[N_NODES]);
    scan3_kernel<<<N_SCAN_BLKS, SCAN_BLK, 0, stream>>>(offsets, bpref, cursor);
    scatter_kernel<<<(N_EDGES + 255) / 256, 256, 0, stream>>>(dst, src, ew, cursor, ssrc, swt);
    cvt_slice_kernel<<<(N_NODES * N_GENES / 8 + 255) / 256, 256, 0, stream>>>(x, xs);

    // ---- 10 sliced propagation iterations ----
    // it0 reads xs; even it -> hsA, odd it -> hsB (d_out scratch); it8 -> hsA.
    // it9 (final) reads hsA, clamps with f32 x, writes f32 node-major d_out.
    const u16* hin = xs;
    for (int it = 0; it < NUM_ITERS - 1; ++it) {
        u16* hout = (it & 1) ? hsB : hsA;
        prop_s_b<<<PROP_GRID, 256, 0, stream>>>(hin, xs, offsets, ssrc, swt, hout);
        hin = hout;
    }
    prop_s_final<<<PROP_GRID, 256, 0, stream>>>(hin, x, offsets, ssrc, swt, out);
}

// Round 8
// 881.813 us; speedup vs baseline: 2.0385x; 2.0385x over previous
//
#include <hip/hip_runtime.h>

#define N_NODES 50000
#define N_GENES 256
#define N_EDGES 800000
#define NUM_ITERS 10
#define SCAN_BLK 1024
#define N_SCAN_BLKS ((N_NODES + SCAN_BLK - 1) / SCAN_BLK)   // 49

#define SLICE_G 128                   // genes per slice (bf16 slice = 12.8 MB)
#define N_SLICES 2                    // one slice per 4-XCD group
#define PROP_GRID 25000               // 2 slices x 12500 node-blocks (4 nodes/block)

typedef unsigned short u16;
struct u16x4 { u16 x, y, z, w; };

static __device__ __forceinline__ float bf2f(u16 b) {
    return __uint_as_float(((unsigned)b) << 16);
}
static __device__ __forceinline__ u16 f2bf(float f) {
    unsigned u = __float_as_uint(f);
    return (u16)((u + 0x7fffu + ((u >> 16) & 1u)) >> 16);   // RNE
}

// ---------------- CSR build (once per launch) -----------------------------

__global__ void hist_kernel(const int* __restrict__ dst, int* __restrict__ counts) {
    int e = blockIdx.x * blockDim.x + threadIdx.x;
    if (e < N_EDGES) atomicAdd(&counts[dst[e]], 1);
}

__global__ __launch_bounds__(SCAN_BLK) void scan1_kernel(
        const int* __restrict__ counts, int* __restrict__ offs,
        int* __restrict__ bsums) {
    int i = blockIdx.x * SCAN_BLK + threadIdx.x;
    int lane = threadIdx.x & 63, wid = threadIdx.x >> 6;
    int v = (i < N_NODES) ? counts[i] : 0;
    int x = v;
    #pragma unroll
    for (int o = 1; o < 64; o <<= 1) {
        int t = __shfl_up(x, o, 64);
        if (lane >= o) x += t;
    }
    __shared__ int wsum[16];
    if (lane == 63) wsum[wid] = x;
    __syncthreads();
    if (wid == 0 && lane < 16) {
        int y = wsum[lane];
        #pragma unroll
        for (int o = 1; o < 16; o <<= 1) {
            int t = __shfl_up(y, o, 64);
            if (lane >= o) y += t;
        }
        wsum[lane] = y;
    }
    __syncthreads();
    int pref = (wid > 0) ? wsum[wid - 1] : 0;
    int incl = x + pref;
    if (i < N_NODES) offs[i] = incl - v;
    if (threadIdx.x == SCAN_BLK - 1) bsums[blockIdx.x] = incl;
}

__global__ void scan2_kernel(const int* __restrict__ bsums,
                             int* __restrict__ bpref,
                             int* __restrict__ offs_total) {
    int lane = threadIdx.x;  // 64 threads
    int v = (lane < N_SCAN_BLKS) ? bsums[lane] : 0;
    int x = v;
    #pragma unroll
    for (int o = 1; o < 64; o <<= 1) {
        int t = __shfl_up(x, o, 64);
        if (lane >= o) x += t;
    }
    if (lane < N_SCAN_BLKS) bpref[lane] = x - v;
    if (lane == 63) offs_total[0] = x;
}

__global__ __launch_bounds__(SCAN_BLK) void scan3_kernel(
        int* __restrict__ offs, const int* __restrict__ bpref,
        int* __restrict__ cursor) {
    int i = blockIdx.x * SCAN_BLK + threadIdx.x;
    if (i < N_NODES) {
        int o = offs[i] + bpref[blockIdx.x];
        offs[i] = o;
        cursor[i] = o;
    }
}

__global__ void scatter_kernel(const int* __restrict__ dst,
                               const int* __restrict__ src,
                               const float* __restrict__ w,
                               int* __restrict__ cursor,
                               int2* __restrict__ edges) {
    int e = blockIdx.x * blockDim.x + threadIdx.x;
    if (e < N_EDGES) {
        int d = dst[e];
        int p = atomicAdd(&cursor[d], 1);
        edges[p] = make_int2(src[e], __float_as_int(w[e]));
    }
}

// x (f32 node-major) -> xs (bf16 slice-major [2][N][128]); 8 genes per thread
__global__ __launch_bounds__(256) void cvt_slice_kernel(const float* __restrict__ x,
                                                        u16* __restrict__ xs) {
    int base = (blockIdx.x * blockDim.x + threadIdx.x) * 8;
    if (base >= N_NODES * N_GENES) return;
    int node = base >> 8;
    int gene = base & 255;
    int slice = gene >> 7;
    int g = gene & 127;            // 8-aligned within slice
    float4 a = *reinterpret_cast<const float4*>(&x[base]);
    float4 b = *reinterpret_cast<const float4*>(&x[base + 4]);
    u16x4 r0 = { f2bf(a.x), f2bf(a.y), f2bf(a.z), f2bf(a.w) };
    u16x4 r1 = { f2bf(b.x), f2bf(b.y), f2bf(b.z), f2bf(b.w) };
    size_t o = (size_t)slice * (N_NODES * SLICE_G) + (size_t)node * SLICE_G + g;
    *reinterpret_cast<u16x4*>(&xs[o])     = r0;
    *reinterpret_cast<u16x4*>(&xs[o + 4]) = r1;
}

// ---------------- 2-slice propagation -------------------------------------
// Slice s (128 genes bf16, 12.8 MB over all nodes) is touched only by blocks
// on XCD group s (blockIdx%8 < 4 -> slice 0, else slice 1) -> per-XCD
// compulsory h-fill halves vs unsliced. One wave per (node, slice): lane
// holds genes 2l..2l+1 (u16x2 gather, 256B/row, fully coalesced). Edge
// metadata loaded lane-parallel + shfl broadcast; 8 gathers in flight.

__global__ __launch_bounds__(256) void prop2_b(
        const u16* __restrict__ hin,   // [2][N][128]
        const u16* __restrict__ xs,    // [2][N][128]
        const int* __restrict__ offsets,
        const int2* __restrict__ edges,
        u16* __restrict__ out) {       // [2][N][128]
    int b = blockIdx.x;
    int slice = ((b & 7) < 4) ? 0 : 1;
    int idx = (b >> 3) * 4 + (b & 3);            // 0..12499 within slice
    int node = idx * 4 + (threadIdx.x >> 6);     // exact: 12500*4 = 50000
    int lane = threadIdx.x & 63;
    int g2 = lane << 1;

    const u16* hs = hin + (size_t)slice * (N_NODES * SLICE_G);
    int beg = offsets[node], end = offsets[node + 1];
    float ax = 0.f, ay = 0.f;

    for (int base = beg; base < end; base += 64) {
        int cnt = end - base;
        if (cnt > 64) cnt = 64;
        int2 el = make_int2(0, 0);
        if (lane < cnt) {
            long long ev = __builtin_nontemporal_load(
                reinterpret_cast<const long long*>(&edges[base + lane]));
            el.x = (int)ev;
            el.y = (int)(ev >> 32);
        }

        int k = 0;
        for (; k + 8 <= cnt; k += 8) {
            int s[8]; float w[8]; unsigned p[8];
            #pragma unroll
            for (int j = 0; j < 8; ++j) {
                s[j] = __shfl(el.x, k + j);
                w[j] = __int_as_float(__shfl(el.y, k + j));
            }
            #pragma unroll
            for (int j = 0; j < 8; ++j)
                p[j] = *reinterpret_cast<const unsigned*>(&hs[(size_t)s[j] * SLICE_G + g2]);
            #pragma unroll
            for (int j = 0; j < 8; ++j) {
                ax += w[j] * bf2f((u16)p[j]);
                ay += w[j] * bf2f((u16)(p[j] >> 16));
            }
        }
        for (; k < cnt; ++k) {
            int   s = __shfl(el.x, k);
            float w = __int_as_float(__shfl(el.y, k));
            unsigned p = *reinterpret_cast<const unsigned*>(&hs[(size_t)s * SLICE_G + g2]);
            ax += w * bf2f((u16)p);
            ay += w * bf2f((u16)(p >> 16));
        }
    }

    size_t o = (size_t)slice * (N_NODES * SLICE_G) + (size_t)node * SLICE_G + g2;
    unsigned ox = __builtin_nontemporal_load(reinterpret_cast<const unsigned*>(&xs[o]));
    u16 b0 = (u16)(ox & 0xFFFFu), b1 = (u16)(ox >> 16);
    u16 r0 = b0 ? b0 : f2bf(ax);   // x >= 0: bits==0 <=> value==0
    u16 r1 = b1 ? b1 : f2bf(ay);
    unsigned res = (unsigned)r0 | ((unsigned)r1 << 16);
    __builtin_nontemporal_store(res, reinterpret_cast<unsigned*>(&out[o]));
}

// Final iteration: same sliced gather, clamp with pristine f32 x, write f32
// node-major output.
__global__ __launch_bounds__(256) void prop2_final(
        const u16* __restrict__ hin,
        const float* __restrict__ x,
        const int* __restrict__ offsets,
        const int2* __restrict__ edges,
        float* __restrict__ out) {
    int b = blockIdx.x;
    int slice = ((b & 7) < 4) ? 0 : 1;
    int idx = (b >> 3) * 4 + (b & 3);
    int node = idx * 4 + (threadIdx.x >> 6);
    int lane = threadIdx.x & 63;
    int g2 = lane << 1;

    const u16* hs = hin + (size_t)slice * (N_NODES * SLICE_G);
    int beg = offsets[node], end = offsets[node + 1];
    float ax = 0.f, ay = 0.f;

    for (int base = beg; base < end; base += 64) {
        int cnt = end - base;
        if (cnt > 64) cnt = 64;
        int2 el = make_int2(0, 0);
        if (lane < cnt) {
            long long ev = __builtin_nontemporal_load(
                reinterpret_cast<const long long*>(&edges[base + lane]));
            el.x = (int)ev;
            el.y = (int)(ev >> 32);
        }

        int k = 0;
        for (; k + 8 <= cnt; k += 8) {
            int s[8]; float w[8]; unsigned p[8];
            #pragma unroll
            for (int j = 0; j < 8; ++j) {
                s[j] = __shfl(el.x, k + j);
                w[j] = __int_as_float(__shfl(el.y, k + j));
            }
            #pragma unroll
            for (int j = 0; j < 8; ++j)
                p[j] = *reinterpret_cast<const unsigned*>(&hs[(size_t)s[j] * SLICE_G + g2]);
            #pragma unroll
            for (int j = 0; j < 8; ++j) {
                ax += w[j] * bf2f((u16)p[j]);
                ay += w[j] * bf2f((u16)(p[j] >> 16));
            }
        }
        for (; k < cnt; ++k) {
            int   s = __shfl(el.x, k);
            float w = __int_as_float(__shfl(el.y, k));
            unsigned p = *reinterpret_cast<const unsigned*>(&hs[(size_t)s * SLICE_G + g2]);
            ax += w * bf2f((u16)p);
            ay += w * bf2f((u16)(p >> 16));
        }
    }

    size_t xo = (size_t)node * N_GENES + slice * SLICE_G + g2;
    float2 o = *reinterpret_cast<const float2*>(&x[xo]);
    float2 r;
    r.x = (o.x != 0.f) ? o.x : ax;
    r.y = (o.y != 0.f) ? o.y : ay;
    *reinterpret_cast<float2*>(&out[xo]) = r;
}

// --------------------------------------------------------------------------

static inline size_t align_up(size_t x, size_t a) { return (x + a - 1) & ~(a - 1); }

extern "C" void kernel_launch(void* const* d_in, const int* in_sizes, int n_in,
                              void* d_out, int out_size, void* d_ws, size_t ws_size,
                              hipStream_t stream) {
    const float* x    = (const float*)d_in[0];   // [N_NODES, N_GENES]
    const int*   eidx = (const int*)d_in[1];     // [2, N_EDGES]: row0 = dst, row1 = src
    const float* ew   = (const float*)d_in[2];   // [N_EDGES]
    float*       out  = (float*)d_out;

    const int* dst = eidx;
    const int* src = eidx + N_EDGES;

    // workspace layout (~59 MB)
    char* ws = (char*)d_ws;
    size_t off = 0;
    u16*   xs      = (u16*) (ws + off); off += align_up((size_t)N_NODES * N_GENES * 2, 256);
    u16*   hsA     = (u16*) (ws + off); off += align_up((size_t)N_NODES * N_GENES * 2, 256);
    int2*  edges   = (int2*)(ws + off); off += align_up((size_t)N_EDGES * 8, 256);
    int*   counts  = (int*) (ws + off); off += align_up((size_t)N_NODES * 4, 256);
    int*   offsets = (int*) (ws + off); off += align_up((size_t)(N_NODES + 1) * 4, 256);
    int*   cursor  = (int*) (ws + off); off += align_up((size_t)N_NODES * 4, 256);
    int*   bsums   = (int*) (ws + off); off += align_up((size_t)N_SCAN_BLKS * 4, 256);
    int*   bpref   = (int*) (ws + off); off += align_up((size_t)N_SCAN_BLKS * 4, 256);
    (void)ws_size;

    u16* hsB = (u16*)d_out;   // d_out doubles as bf16 slice-major scratch (25.6 MB)

    // ---- build CSR by destination + slice-major bf16 copy of x ----
    hipMemsetAsync(counts, 0, (size_t)N_NODES * 4, stream);
    hist_kernel<<<(N_EDGES + 255) / 256, 256, 0, stream>>>(dst, counts);
    scan1_kernel<<<N_SCAN_BLKS, SCAN_BLK, 0, stream>>>(counts, offsets, bsums);
    scan2_kernel<<<1, 64, 0, stream>>>(bsums, bpref, &offsets[N_NODES]);
    scan3_kernel<<<N_SCAN_BLKS, SCAN_BLK, 0, stream>>>(offsets, bpref, cursor);
    scatter_kernel<<<(N_EDGES + 255) / 256, 256, 0, stream>>>(dst, src, ew, cursor, edges);
    cvt_slice_kernel<<<(N_NODES * N_GENES / 8 + 255) / 256, 256, 0, stream>>>(x, xs);

    // ---- 10 sliced propagation iterations ----
    // it0 reads xs; even it -> hsA, odd it -> hsB (d_out scratch); it8 -> hsA.
    // it9 (final) reads hsA, clamps with f32 x, writes f32 node-major d_out.
    const u16* hin = xs;
    for (int it = 0; it < NUM_ITERS - 1; ++it) {
        u16* hout = (it & 1) ? hsB : hsA;
        prop2_b<<<PROP_GRID, 256, 0, stream>>>(hin, xs, offsets, edges, hout);
        hin = hout;
    }
    prop2_final<<<PROP_GRID, 256, 0, stream>>>(hin, x, offsets, edges, out);
}